// Round 2
// baseline (217.664 us; speedup 1.0000x reference)
//
#include <hip/hip_runtime.h>
#include <hip/hip_bf16.h>

#define N_  128
#define C_  256
#define T_  48
#define V_  25

// One block per (n, segment): owns x[n, :, t0:t0+3, :] = 256*75 floats.
// Reads x once (coalesced, staged to LDS as bf16), computes the whole gate
// pipeline in-block, applies gate from LDS, writes out once.
__global__ __launch_bounds__(256, 3) void k_fused(
    const float* __restrict__ x,
    const float* __restrict__ wsq, const float* __restrict__ bsq,
    const float* __restrict__ gamma, const float* __restrict__ beta,
    const float* __restrict__ rmean, const float* __restrict__ rvar,
    const float* __restrict__ wc1, const float* __restrict__ bc1,
    const float* __restrict__ wex, const float* __restrict__ bex,
    float* __restrict__ out)
{
    __shared__ __hip_bfloat16 xs[19200];  // [c][tt][v], idx = c*75 + tt*25 + v
    __shared__ float xb[768];             // v-means [c][tt]
    __shared__ float part[768];           // squeeze partials [g*16+r][tt]
    __shared__ float ybn[48];             // [tt][r] squeeze+BN
    __shared__ float y1[48];              // [tt][s] conv1
    __shared__ float mv[48];              // [tt][r] temporal diff
    __shared__ float gs[768];             // gate [c][tt]

    const unsigned tid = threadIdx.x;
    const unsigned n   = blockIdx.x >> 4;
    const unsigned seg = blockIdx.x & 15u;
    const float* xg = x   + (size_t)n * (C_ * T_ * V_) + seg * 75u;
    float*       og = out + (size_t)n * (C_ * T_ * V_) + seg * 75u;

    // ---- Phase A: coalesced global read -> bf16 LDS stage ----
    #pragma unroll
    for (unsigned i = 0; i < 75; ++i) {
        unsigned idx = i * 256u + tid;          // 0..19199
        unsigned c   = idx / 75u;
        unsigned off = idx - c * 75u;
        xs[idx] = __float2bfloat16(xg[c * 1200u + off]);
    }
    // prefetch expand weights (used in B4) while LDS settles
    float wexr[16];
    #pragma unroll
    for (int r = 0; r < 16; ++r) wexr[r] = wex[tid * 16u + r];
    const float bexr = bex[tid];
    __syncthreads();

    // ---- v-mean reduce: thread = channel; stride-75(ushort) rows ----
    {
        float s0 = 0.f, s1 = 0.f, s2 = 0.f;
        #pragma unroll
        for (int v = 0; v < 25; ++v) {
            s0 += __bfloat162float(xs[tid * 75u + v]);
            s1 += __bfloat162float(xs[tid * 75u + 25u + v]);
            s2 += __bfloat162float(xs[tid * 75u + 50u + v]);
        }
        xb[tid * 3u + 0] = s0 * 0.04f;
        xb[tid * 3u + 1] = s1 * 0.04f;
        xb[tid * 3u + 2] = s2 * 0.04f;
    }
    __syncthreads();

    // ---- B1: squeeze conv partials: thread = (g, r) ----
    {
        unsigned r = tid & 15u, g = tid >> 4;
        float p0 = 0.f, p1 = 0.f, p2 = 0.f;
        #pragma unroll
        for (unsigned cc = 0; cc < 16; ++cc) {
            unsigned c = g * 16u + cc;
            float w = wsq[r * 256u + c];
            p0 += xb[c * 3u + 0] * w;
            p1 += xb[c * 3u + 1] * w;
            p2 += xb[c * 3u + 2] * w;
        }
        part[tid * 3u + 0] = p0;
        part[tid * 3u + 1] = p1;
        part[tid * 3u + 2] = p2;
    }
    __syncthreads();

    // ---- B1b: finalize squeeze + BatchNorm (48 threads) ----
    if (tid < 48) {
        unsigned tt = tid >> 4, r = tid & 15u;
        float acc = 0.f;
        #pragma unroll
        for (unsigned g = 0; g < 16; ++g) acc += part[(g * 16u + r) * 3u + tt];
        float sc = gamma[r] * rsqrtf(rvar[r] + 1e-5f);
        float sh = beta[r] - rmean[r] * sc;
        ybn[tt * 16u + r] = (acc + bsq[r]) * sc + sh;
    }
    __syncthreads();

    // ---- B2: conv1 (48 threads) ----
    if (tid < 48) {
        unsigned tt = tid >> 4, s = tid & 15u;
        float acc = bc1[s];
        #pragma unroll
        for (int r = 0; r < 16; ++r) acc += ybn[tt * 16u + r] * wc1[s * 16u + r];
        y1[tt * 16u + s] = acc;
    }
    __syncthreads();

    // ---- B3: temporal diff, zero last frame of segment ----
    if (tid < 48) {
        unsigned tt = tid >> 4, r = tid & 15u;
        mv[tid] = (tt < 2) ? (y1[(tt + 1) * 16u + r] - ybn[tt * 16u + r]) : 0.f;
    }
    __syncthreads();

    // ---- B4: expand conv + sigmoid: thread = channel ----
    #pragma unroll
    for (int tt = 0; tt < 3; ++tt) {
        float a = bexr;
        #pragma unroll
        for (int r = 0; r < 16; ++r) a += mv[tt * 16 + r] * wexr[r];
        gs[tid * 3u + tt] = 1.f / (1.f + expf(-a));
    }
    __syncthreads();

    // ---- Phase C: apply gate from LDS, coalesced store ----
    #pragma unroll
    for (unsigned i = 0; i < 75; ++i) {
        unsigned idx = i * 256u + tid;
        unsigned c   = idx / 75u;
        unsigned off = idx - c * 75u;
        unsigned tt  = (off * 41u) >> 10;       // off/25 for off in [0,75)
        og[c * 1200u + off] = __bfloat162float(xs[idx]) * gs[c * 3u + tt];
    }
}

extern "C" void kernel_launch(void* const* d_in, const int* in_sizes, int n_in,
                              void* d_out, int out_size, void* d_ws, size_t ws_size,
                              hipStream_t stream) {
    const float* x     = (const float*)d_in[0];
    const float* wsq   = (const float*)d_in[1];
    const float* bsq   = (const float*)d_in[2];
    const float* gamma = (const float*)d_in[3];
    const float* beta  = (const float*)d_in[4];
    const float* rmean = (const float*)d_in[5];
    const float* rvar  = (const float*)d_in[6];
    const float* wc1   = (const float*)d_in[7];
    const float* bc1   = (const float*)d_in[8];
    const float* wex   = (const float*)d_in[9];
    const float* bex   = (const float*)d_in[10];

    k_fused<<<N_ * (T_ / 3), 256, 0, stream>>>(x, wsq, bsq, gamma, beta,
                                               rmean, rvar, wc1, bc1, wex, bex,
                                               (float*)d_out);
}

// Round 3
// 92.008 us; speedup vs baseline: 2.3657x; 2.3657x over previous
//
#include <hip/hip_runtime.h>
#include <hip/hip_bf16.h>

#define N_  128
#define C_  256
#define T_  48
#define V_  25

__device__ __forceinline__ float b2f(unsigned short u) {
    union { float f; unsigned i; } c; c.i = ((unsigned)u) << 16; return c.f;
}
__device__ __forceinline__ unsigned short f2b(float f) {
    __hip_bfloat16 h = __float2bfloat16(f);
    return *(unsigned short*)&h;
}

// Block = (n, seg-group of 4 segments = 12 frames). Per channel: 300 contiguous,
// 16B-aligned floats. Reads x once (float4), v-means via bf16 LDS staging,
// gate math in-block, apply re-reads x as f32 (L2/L3-hot), writes aligned float4.
__global__ __launch_bounds__(512, 4) void k_fused2(
    const float* __restrict__ x,
    const float* __restrict__ wsq, const float* __restrict__ bsq,
    const float* __restrict__ gamma, const float* __restrict__ beta,
    const float* __restrict__ rmean, const float* __restrict__ rvar,
    const float* __restrict__ wc1, const float* __restrict__ bc1,
    const float* __restrict__ wex, const float* __restrict__ bex,
    float* __restrict__ out)
{
    __shared__ __align__(16) unsigned short sbuf[64 * 300]; // 38400 B bf16 stage
    __shared__ float xb[256 * 12];    // v-means [c][tl]         12288 B
    __shared__ float part[384];       // squeeze partials [t][r][h] 1536 B
    __shared__ float ybn[192];        // [t][r]                   768 B
    __shared__ float y1[192];         // [t][s]                   768 B
    __shared__ float mv[192];         // [t][r]                   768 B
    __shared__ float gs[256 * 12];    // gate [c][tl]            12288 B

    const int tid = threadIdx.x;
    const unsigned bid = blockIdx.x;
    const unsigned o   = (bid & 7u) * 64u + (bid >> 3);  // XCD-chunk swizzle (512%8==0, bijective)
    const unsigned n   = o >> 2;
    const unsigned sg  = o & 3u;

    const float* xg = x   + (size_t)n * 307200u + sg * 300u;  // + c*1200 + pos*4
    float*       og = out + (size_t)n * 307200u + sg * 300u;

    // ---- Phase A: 4 channel-groups: stage f32->bf16, reduce v-means ----
    for (int cg = 0; cg < 4; ++cg) {
        for (int it = 0; it < 10; ++it) {
            int j = it * 512 + tid;                 // float4 index, 0..4799
            if (j < 4800) {
                int cl  = j / 75;
                int pos = j - cl * 75;
                const float4 v = *(const float4*)(xg + (unsigned)(cg * 64 + cl) * 1200u + (unsigned)pos * 4u);
                ushort4 u;
                u.x = f2b(v.x); u.y = f2b(v.y); u.z = f2b(v.z); u.w = f2b(v.w);
                *(ushort4*)(sbuf + j * 4) = u;
            }
        }
        __syncthreads();
        for (int p = tid; p < 768; p += 512) {      // 64 ch x 12 frames
            int cl = p / 12, t = p - cl * 12;
            const unsigned short* row = sbuf + cl * 300 + t * 25;
            float s = 0.f;
            #pragma unroll
            for (int v = 0; v < 25; ++v) s += b2f(row[v]);
            xb[(cg * 64 + cl) * 12 + t] = s * (1.f / 25.f);
        }
        __syncthreads();
    }

    // ---- Phase B1: squeeze conv partials: thread=(t, r, half) ----
    if (tid < 384) {
        int t = tid >> 5;
        int rh = tid & 31;
        int r = rh >> 1, h = rh & 1;
        const float* wrow = wsq + r * 256 + h * 128;
        float acc = 0.f;
        #pragma unroll 8
        for (int i = 0; i < 128; ++i) acc += xb[(h * 128 + i) * 12 + t] * wrow[i];
        part[tid] = acc;
    }
    __syncthreads();
    // ---- B1b: combine + BatchNorm ----
    if (tid < 192) {
        int t = tid >> 4, r = tid & 15;
        float acc = part[t * 32 + r * 2] + part[t * 32 + r * 2 + 1];
        float sc = gamma[r] * rsqrtf(rvar[r] + 1e-5f);
        ybn[t * 16 + r] = (acc + bsq[r]) * sc + (beta[r] - rmean[r] * sc);
    }
    __syncthreads();
    // ---- B2: conv1 ----
    if (tid < 192) {
        int t = tid >> 4, s = tid & 15;
        float acc = bc1[s];
        #pragma unroll
        for (int r = 0; r < 16; ++r) acc += ybn[t * 16 + r] * wc1[s * 16 + r];
        y1[t * 16 + s] = acc;
    }
    __syncthreads();
    // ---- B3: temporal diff (segment-local; sg*12 is a multiple of 3) ----
    if (tid < 192) {
        int t = tid >> 4, r = tid & 15;
        mv[tid] = ((t % 3) < 2) ? (y1[(t + 1) * 16 + r] - ybn[t * 16 + r]) : 0.f;
    }
    __syncthreads();
    // ---- B4: expand + sigmoid: thread=(c, t-half) ----
    {
        int c = tid & 255, th = tid >> 8;
        float wexr[16];
        #pragma unroll
        for (int r = 0; r < 16; ++r) wexr[r] = wex[c * 16 + r];
        float be = bex[c];
        for (int t = th * 6; t < th * 6 + 6; ++t) {
            float a = be;
            #pragma unroll
            for (int r = 0; r < 16; ++r) a += mv[t * 16 + r] * wexr[r];
            gs[c * 12 + t] = 1.f / (1.f + expf(-a));
        }
    }
    __syncthreads();

    // ---- Phase D: apply gate; f32 re-read (cache-hot), aligned float4 store ----
    for (int it = 0; it < 38; ++it) {
        int j = it * 512 + tid;                     // float4 index, 0..19199
        if (j < 19200) {
            int c = j / 75, pos = j - c * 75;
            const float4 v = *(const float4*)(xg + (unsigned)c * 1200u + (unsigned)pos * 4u);
            int p4  = pos * 4;
            int t0  = p4 / 25;
            int t3  = (p4 + 3) / 25;
            int rem = p4 - t0 * 25;
            float g0 = gs[c * 12 + t0];
            float g3 = gs[c * 12 + t3];
            float4 ov;
            ov.x = v.x * g0;
            ov.y = v.y * ((rem + 1 < 25) ? g0 : g3);
            ov.z = v.z * ((rem + 2 < 25) ? g0 : g3);
            ov.w = v.w * ((rem + 3 < 25) ? g0 : g3);
            *(float4*)(og + (unsigned)c * 1200u + (unsigned)pos * 4u) = ov;
        }
    }
}

extern "C" void kernel_launch(void* const* d_in, const int* in_sizes, int n_in,
                              void* d_out, int out_size, void* d_ws, size_t ws_size,
                              hipStream_t stream) {
    const float* x     = (const float*)d_in[0];
    const float* wsq   = (const float*)d_in[1];
    const float* bsq   = (const float*)d_in[2];
    const float* gamma = (const float*)d_in[3];
    const float* beta  = (const float*)d_in[4];
    const float* rmean = (const float*)d_in[5];
    const float* rvar  = (const float*)d_in[6];
    const float* wc1   = (const float*)d_in[7];
    const float* bc1   = (const float*)d_in[8];
    const float* wex   = (const float*)d_in[9];
    const float* bex   = (const float*)d_in[10];

    k_fused2<<<512, 512, 0, stream>>>(x, wsq, bsq, gamma, beta,
                                      rmean, rvar, wc1, bc1, wex, bex,
                                      (float*)d_out);
}